// Round 7
// baseline (524.463 us; speedup 1.0000x reference)
//
#include <hip/hip_runtime.h>
#include <hip/hip_bf16.h>
#include <stdint.h>

// Problem constants (from reference): B=4, S=2048, D=1024, H=16, DK=64
#define S_LEN 2048
#define D_DIM 1024
#define NH    16
#define DKH   64
#define BATCH 4

typedef __bf16 bf16x8 __attribute__((ext_vector_type(8)));
typedef float  f32x4  __attribute__((ext_vector_type(4)));

__device__ __forceinline__ unsigned short f2bf(float x) {
  unsigned u = __float_as_uint(x);
  return (unsigned short)((u + 0x7FFFu + ((u >> 16) & 1u)) >> 16);  // RNE
}
__device__ __forceinline__ float bf2f(unsigned short b) {
  return __uint_as_float(((unsigned)b) << 16);
}

// async global->LDS, 16B per lane. LDS dest is wave-uniform base + lane*16.
__device__ __forceinline__ void gll16(const void* g, void* l) {
  __builtin_amdgcn_global_load_lds((const __attribute__((address_space(1))) unsigned*)g,
                                   (__attribute__((address_space(3))) unsigned*)l, 16, 0, 0);
}

#define MFMA(a, b, c) __builtin_amdgcn_mfma_f32_16x16x32_bf16(a, b, c, 0, 0, 0)

// ---------------------------------------------------------------------------
// Convert fp32 -> bf16 hi/lo, elementwise (for X / inputs), 4 floats/thread
// ---------------------------------------------------------------------------
__global__ void k_split(const float4* __restrict__ x, ushort4* __restrict__ hi,
                        ushort4* __restrict__ lo, int n4) {
  int i = blockIdx.x * 256 + threadIdx.x;
  if (i >= n4) return;
  float4 v = x[i];
  ushort4 h, l;
  h.x = f2bf(v.x); l.x = f2bf(v.x - bf2f(h.x));
  h.y = f2bf(v.y); l.y = f2bf(v.y - bf2f(h.y));
  h.z = f2bf(v.z); l.z = f2bf(v.z - bf2f(h.z));
  h.w = f2bf(v.w); l.w = f2bf(v.w - bf2f(h.w));
  hi[i] = h;
  lo[i] = l;
}

// ---------------------------------------------------------------------------
// Convert + transpose weight: W[K][N] fp32 -> Wt hi/lo [N][K] bf16
// ---------------------------------------------------------------------------
__global__ void k_wt(const float* __restrict__ W, unsigned short* __restrict__ hi,
                     unsigned short* __restrict__ lo) {
  __shared__ float t[64][65];
  const int tid = threadIdx.x;
  const int k0 = blockIdx.x * 64, n0 = blockIdx.y * 64;
#pragma unroll
  for (int i = 0; i < 16; i++) {
    int idx = i * 256 + tid;
    int r = idx >> 6, c = idx & 63;
    t[r][c] = W[(size_t)(k0 + r) * D_DIM + n0 + c];
  }
  __syncthreads();
#pragma unroll
  for (int i = 0; i < 16; i++) {
    int idx = i * 256 + tid;
    int r = idx >> 6, c = idx & 63;
    float v = t[c][r];  // = W[k0+c][n0+r]
    unsigned short h = f2bf(v);
    size_t o = (size_t)(n0 + r) * D_DIM + k0 + c;
    hi[o] = h;
    lo[o] = f2bf(v - bf2f(h));
  }
}

// ---------------------------------------------------------------------------
// Shared hi/lo 3-pass GEMM core: computes a 128x128 C tile at (m0, n0) from
// A (hi/lo, [8192][1024]) and Bt (hi/lo, [N][K] transposed weights).
// Results left in acc[4][4] (wave-level 2x2 of 64x64).
// ---------------------------------------------------------------------------
__device__ __forceinline__ void gemm_core(
    const unsigned short* __restrict__ Ahi, const unsigned short* __restrict__ Alo,
    const unsigned short* __restrict__ Bth, const unsigned short* __restrict__ Btl,
    int m0, int n0, char* smem, f32x4 (&acc)[4][4]) {
  constexpr int K = 1024;
  char* sAh = smem;
  char* sAl = smem + 16384;
  char* sBh = smem + 32768;
  char* sBl = smem + 49152;

  const int tid = threadIdx.x;
  const int lane = tid & 63, w = tid >> 6;
  const int wr = w >> 1, wc = w & 1;

  int gofs[4], lofs[4];
#pragma unroll
  for (int i = 0; i < 4; i++) {
    int c = (w * 4 + i) * 64 + lane;
    int row = c >> 3, s = c & 7;
    int sp = s ^ (row & 7);
    gofs[i] = row * K + sp * 8;
    lofs[i] = (w * 4 + i) * 1024;
  }
  const unsigned short* pAh = Ahi + (size_t)m0 * K;
  const unsigned short* pAl = Alo + (size_t)m0 * K;
  const unsigned short* pBh = Bth + (size_t)n0 * K;
  const unsigned short* pBl = Btl + (size_t)n0 * K;

  for (int kt = 0; kt < K / 64; ++kt) {
    const int ko = kt * 64;
#pragma unroll
    for (int i = 0; i < 4; i++) {
      gll16(pAh + ko + gofs[i], sAh + lofs[i]);
      gll16(pAl + ko + gofs[i], sAl + lofs[i]);
      gll16(pBh + ko + gofs[i], sBh + lofs[i]);
      gll16(pBl + ko + gofs[i], sBl + lofs[i]);
    }
    __syncthreads();
#pragma unroll
    for (int kk = 0; kk < 2; kk++) {
      bf16x8 ah[4], al[4], bh[4], bl[4];
      const int cch = kk * 4 + (lane >> 4);
#pragma unroll
      for (int mr = 0; mr < 4; mr++) {
        int row = wr * 64 + mr * 16 + (lane & 15);
        int off = row * 128 + ((cch ^ (row & 7)) << 4);
        ah[mr] = *(const bf16x8*)(sAh + off);
        al[mr] = *(const bf16x8*)(sAl + off);
      }
#pragma unroll
      for (int nr = 0; nr < 4; nr++) {
        int row = wc * 64 + nr * 16 + (lane & 15);
        int off = row * 128 + ((cch ^ (row & 7)) << 4);
        bh[nr] = *(const bf16x8*)(sBh + off);
        bl[nr] = *(const bf16x8*)(sBl + off);
      }
#pragma unroll
      for (int mr = 0; mr < 4; mr++)
#pragma unroll
        for (int nr = 0; nr < 4; nr++) {
          acc[mr][nr] = MFMA(ah[mr], bh[nr], acc[mr][nr]);
          acc[mr][nr] = MFMA(ah[mr], bl[nr], acc[mr][nr]);
          acc[mr][nr] = MFMA(al[mr], bh[nr], acc[mr][nr]);
        }
    }
    __syncthreads();
  }
}

// ---------------------------------------------------------------------------
// Fused QKV projection. grid = (64 m-tiles, 24 = mat*8 + n-tile).
// m on blockIdx.x => all 24 blocks of an m-row have id%8 equal -> same XCD,
// so the A-row (hi+lo, 512KB) is fetched once per XCD (L2-local).
// mat 0: Q (escale 1) -> Qh/Ql [M][N];  mat 1: K (escale 1/8) -> Kh/Kl;
// mat 2: V -> Vt hi/lo [b][h][d][s].
// ---------------------------------------------------------------------------
__global__ __launch_bounds__(256, 2) void gemm_qkv(
    const unsigned short* __restrict__ Ahi, const unsigned short* __restrict__ Alo,
    const unsigned short* __restrict__ Wqh, const unsigned short* __restrict__ Wql,
    const unsigned short* __restrict__ Wkh, const unsigned short* __restrict__ Wkl,
    const unsigned short* __restrict__ Wvh, const unsigned short* __restrict__ Wvl,
    unsigned short* __restrict__ Qh, unsigned short* __restrict__ Ql,
    unsigned short* __restrict__ Kh, unsigned short* __restrict__ Kl,
    unsigned short* __restrict__ Vth, unsigned short* __restrict__ Vtl) {
  constexpr int N = 1024;
  extern __shared__ char smem[];
  const int m0 = blockIdx.x * 128;
  const int mat = blockIdx.y >> 3;
  const int n0 = (blockIdx.y & 7) * 128;

  const unsigned short* Bth = mat == 0 ? Wqh : mat == 1 ? Wkh : Wvh;
  const unsigned short* Btl = mat == 0 ? Wql : mat == 1 ? Wkl : Wvl;
  unsigned short* Chi = mat == 0 ? Qh : mat == 1 ? Kh : Vth;
  unsigned short* Clo = mat == 0 ? Ql : mat == 1 ? Kl : Vtl;
  const float esc = mat == 1 ? 0.125f : 1.0f;

  f32x4 acc[4][4] = {};
  gemm_core(Ahi, Alo, Bth, Btl, m0, n0, smem, acc);

  const int lane = threadIdx.x & 63, w = threadIdx.x >> 6;
  const int wr = w >> 1, wc = w & 1;
#pragma unroll
  for (int mr = 0; mr < 4; mr++)
#pragma unroll
    for (int nr = 0; nr < 4; nr++)
#pragma unroll
      for (int j = 0; j < 4; j++) {
        int row = m0 + wr * 64 + mr * 16 + (lane >> 4) * 4 + j;
        int col = n0 + wc * 64 + nr * 16 + (lane & 15);
        float v = acc[mr][nr][j];
        if (mat < 2) {
          v *= esc;
          size_t o = (size_t)row * N + col;
          unsigned short hh = f2bf(v);
          Chi[o] = hh;
          Clo[o] = f2bf(v - bf2f(hh));
        } else {
          int bi = row >> 11, s = row & (S_LEN - 1);
          int hh2 = col >> 6, d = col & (DKH - 1);
          size_t o = ((size_t)(bi * NH + hh2) * DKH + d) * S_LEN + s;
          unsigned short hh = f2bf(v);
          Chi[o] = hh;
          Clo[o] = f2bf(v - bf2f(hh));
        }
      }
}

// ---------------------------------------------------------------------------
// Final GEMM (O @ Wo), fp32 out. m on blockIdx.x (grid 64 x 8) for XCD
// locality of A rows.
// ---------------------------------------------------------------------------
__global__ __launch_bounds__(256, 2) void gemm_wo(
    const unsigned short* __restrict__ Ahi, const unsigned short* __restrict__ Alo,
    const unsigned short* __restrict__ Bth, const unsigned short* __restrict__ Btl,
    float* __restrict__ Cf) {
  constexpr int N = 1024;
  extern __shared__ char smem[];
  const int m0 = blockIdx.x * 128, n0 = blockIdx.y * 128;

  f32x4 acc[4][4] = {};
  gemm_core(Ahi, Alo, Bth, Btl, m0, n0, smem, acc);

  const int lane = threadIdx.x & 63, w = threadIdx.x >> 6;
  const int wr = w >> 1, wc = w & 1;
#pragma unroll
  for (int mr = 0; mr < 4; mr++)
#pragma unroll
    for (int nr = 0; nr < 4; nr++)
#pragma unroll
      for (int j = 0; j < 4; j++) {
        int row = m0 + wr * 64 + mr * 16 + (lane >> 4) * 4 + j;
        int col = n0 + wc * 64 + nr * 16 + (lane & 15);
        Cf[(size_t)row * N + col] = acc[mr][nr][j];
      }
}

// ---------------------------------------------------------------------------
// Flash attention v5: KVBLK=32, double-buffered, ONE barrier per tile,
// LDS = 8*4KB + 4*2KB = 40KB -> 4 blocks/CU (16 waves/CU).
// Cheap softmax (no max-tracking, deferred row-sum, K pre-scaled by 1/8).
// Block = 256 thr = 4 waves, 128 q rows (wave owns 32). grid.x = (b,h).
// QK^T 3-pass hi/lo (24 MFMA/tile/wave); PV 2-pass (16 MFMA/tile/wave).
// ---------------------------------------------------------------------------
__global__ __launch_bounds__(256, 4) void attn5(
    const unsigned short* __restrict__ Qh, const unsigned short* __restrict__ Ql,
    const unsigned short* __restrict__ Kh, const unsigned short* __restrict__ Kl,
    const unsigned short* __restrict__ Vth, const unsigned short* __restrict__ Vtl,
    const int* __restrict__ mask,
    unsigned short* __restrict__ Oh, unsigned short* __restrict__ Ol) {
  // buffer sets: K tile [32 keys][64 dk] (4KB), Vt tile [64 d][32 s] (4KB)
  __shared__ char sKh0[4096], sKl0[4096], sVh0[4096], sVl0[4096];
  __shared__ char sKh1[4096], sKl1[4096], sVh1[4096], sVl1[4096];
  __shared__ char sP[4][2048];  // per-wave P hi: [32 rows][32 keys] bf16, XOR(row&3)

  const int tid = threadIdx.x, lane = tid & 63, w = tid >> 6;
  const int bh = blockIdx.x, b = bh >> 4, h = bh & (NH - 1);
  const int q0 = blockIdx.y * 128 + w * 32;
  const int lo16 = lane & 15, hi4 = lane >> 4;

  // Q fragments for 2 row-groups x 2 k-chunks (scores pre-scaled via K*0.125)
  bf16x8 qh[2][2], ql[2][2];
#pragma unroll
  for (int g = 0; g < 2; g++)
#pragma unroll
    for (int kk = 0; kk < 2; kk++) {
      size_t base = ((size_t)(b * S_LEN + q0 + g * 16 + lo16)) * D_DIM + h * DKH + kk * 32 + hi4 * 8;
      qh[g][kk] = *(const bf16x8*)(Qh + base);
      ql[g][kk] = *(const bf16x8*)(Ql + base);
    }

  // staging: 256 chunks of 16B per tile-matrix; this thread owns chunk c.
  const int c = w * 64 + lane;             // 0..255
  const int krow = c >> 3;                 // K tile row (0..31), 8 chunks/row
  const int kcol = ((c & 7) ^ (krow & 7)) * 8;
  const int vrow = c >> 2;                 // V tile row (0..63), 4 chunks/row
  const int vcol = ((c & 3) ^ (vrow & 3)) * 8;
  const int ldst = w * 1024;               // wave-uniform LDS dest base

  float lsum[2][4] = {};
  f32x4 oacc[2][4] = {};
  char* sPw = sP[w];

  const size_t kbase = (size_t)b * S_LEN * D_DIM + h * DKH;
  const size_t vbase = (size_t)bh * DKH * S_LEN;
  const int* mrow = mask + b * S_LEN;

  auto STAGE = [&](char* dKh, char* dKl, char* dVh, char* dVl, int sk0) {
    size_t gk = kbase + (size_t)(sk0 + krow) * D_DIM + kcol;
    gll16(Kh + gk, dKh + ldst);
    gll16(Kl + gk, dKl + ldst);
    size_t gv = vbase + (size_t)vrow * S_LEN + sk0 + vcol;
    gll16(Vth + gv, dVh + ldst);
    gll16(Vtl + gv, dVl + ldst);
  };

  auto COMPUTE = [&](const char* cKh, const char* cKl, const char* cVh,
                     const char* cVl, int sk0) {
    // ---- QK^T (3-pass hi/lo), 24 MFMA ----
    f32x4 sc[2][2] = {};
    __builtin_amdgcn_s_setprio(1);
#pragma unroll
    for (int nr = 0; nr < 2; nr++) {
      int row = nr * 16 + lo16;
      int off0 = row * 128 + ((hi4 ^ (row & 7)) << 4);
      int off1 = row * 128 + (((4 + hi4) ^ (row & 7)) << 4);
      bf16x8 kh0 = *(const bf16x8*)(cKh + off0);
      bf16x8 kh1 = *(const bf16x8*)(cKh + off1);
      bf16x8 kl0 = *(const bf16x8*)(cKl + off0);
      bf16x8 kl1 = *(const bf16x8*)(cKl + off1);
#pragma unroll
      for (int g = 0; g < 2; g++) {
        sc[g][nr] = MFMA(qh[g][0], kh0, sc[g][nr]);
        sc[g][nr] = MFMA(qh[g][1], kh1, sc[g][nr]);
        sc[g][nr] = MFMA(qh[g][0], kl0, sc[g][nr]);
        sc[g][nr] = MFMA(qh[g][1], kl1, sc[g][nr]);
        sc[g][nr] = MFMA(ql[g][0], kh0, sc[g][nr]);
        sc[g][nr] = MFMA(ql[g][1], kh1, sc[g][nr]);
      }
    }
    __builtin_amdgcn_s_setprio(0);

    // ---- exp + deferred sum + P->LDS (hi only) ----
#pragma unroll
    for (int nr = 0; nr < 2; nr++) {
      float bias = mrow[sk0 + nr * 16 + lo16] ? 0.f : -1e9f;
#pragma unroll
      for (int g = 0; g < 2; g++)
#pragma unroll
        for (int j = 0; j < 4; j++) {
          float p = __expf(sc[g][nr][j] + bias);
          lsum[g][j] += p;
          int row = g * 16 + hi4 * 4 + j;
          int colb = (nr * 16 + lo16) * 2;
          *(unsigned short*)(sPw + row * 64 + (colb ^ ((row & 3) << 4))) = f2bf(p);
        }
    }

    // ---- P A-fragments (same wave; compiler inserts lgkmcnt) ----
    bf16x8 pa[2];
#pragma unroll
    for (int g = 0; g < 2; g++) {
      int row = g * 16 + lo16;
      pa[g] = *(const bf16x8*)(sPw + row * 64 + ((hi4 * 16) ^ ((row & 3) << 4)));
    }

    // ---- PV (2-pass), 16 MFMA ----
    __builtin_amdgcn_s_setprio(1);
#pragma unroll
    for (int f = 0; f < 4; f++) {
      int vr = f * 16 + lo16;
      int voff = vr * 64 + ((hi4 ^ (vr & 3)) << 4);
      bf16x8 vh = *(const bf16x8*)(cVh + voff);
      bf16x8 vl = *(const bf16x8*)(cVl + voff);
#pragma unroll
      for (int g = 0; g < 2; g++) {
        oacc[g][f] = MFMA(pa[g], vh, oacc[g][f]);
        oacc[g][f] = MFMA(pa[g], vl, oacc[g][f]);
      }
    }
    __builtin_amdgcn_s_setprio(0);
  };

  // prologue: stage tile 0 into set 0
  STAGE(sKh0, sKl0, sVh0, sVl0, 0);
  __syncthreads();

  // main loop: 64 tiles of 32 keys, unrolled x2 (compile-time buffer identity)
  for (int kt = 0; kt < S_LEN / 32; kt += 2) {
    const int sk0 = kt * 32;
    STAGE(sKh1, sKl1, sVh1, sVl1, sk0 + 32);
    COMPUTE(sKh0, sKl0, sVh0, sVl0, sk0);
    __syncthreads();
    if (kt + 2 < S_LEN / 32) STAGE(sKh0, sKl0, sVh0, sVl0, sk0 + 64);
    COMPUTE(sKh1, sKl1, sVh1, sVl1, sk0 + 32);
    __syncthreads();
  }

  // final row-sum reduce (keys spread over lane&15 within each 16-lane group)
  float inv[2][4];
#pragma unroll
  for (int g = 0; g < 2; g++)
#pragma unroll
    for (int j = 0; j < 4; j++) {
      float s = lsum[g][j];
      s += __shfl_xor(s, 1);
      s += __shfl_xor(s, 2);
      s += __shfl_xor(s, 4);
      s += __shfl_xor(s, 8);
      inv[g][j] = 1.f / s;
    }

#pragma unroll
  for (int g = 0; g < 2; g++)
#pragma unroll
    for (int f = 0; f < 4; f++)
#pragma unroll
      for (int j = 0; j < 4; j++) {
        int row = q0 + g * 16 + hi4 * 4 + j;
        int col = h * DKH + f * 16 + lo16;
        float v = oacc[g][f][j] * inv[g][j];
        size_t o = ((size_t)(b * S_LEN + row)) * D_DIM + col;
        unsigned short hh = f2bf(v);
        Oh[o] = hh;
        Ol[o] = f2bf(v - bf2f(hh));
      }
}

// ---------------------------------------------------------------------------
extern "C" void kernel_launch(void* const* d_in, const int* in_sizes, int n_in,
                              void* d_out, int out_size, void* d_ws, size_t ws_size,
                              hipStream_t stream) {
  const float* X = (const float*)d_in[0];
  const int* mask = (const int*)d_in[1];
  const float* Wq = (const float*)d_in[2];
  const float* Wk = (const float*)d_in[3];
  const float* Wv = (const float*)d_in[4];
  const float* Wo = (const float*)d_in[5];
  float* out = (float*)d_out;

  const size_t MB = 1024 * 1024;
  if (ws_size < 144 * MB) return;  // insufficient scratch -> visible failure

  char* ws = (char*)d_ws;
  unsigned short* Xh = (unsigned short*)(ws);            // 16MB  (later Oh)
  unsigned short* Xl = (unsigned short*)(ws + 16 * MB);  // 16MB  (later Ol)
  unsigned short* Wqth = (unsigned short*)(ws + 32 * MB);
  unsigned short* Wqtl = Wqth + 1024 * 1024;
  unsigned short* Wkth = Wqtl + 1024 * 1024;
  unsigned short* Wktl = Wkth + 1024 * 1024;
  unsigned short* Wvth = Wktl + 1024 * 1024;
  unsigned short* Wvtl = Wvth + 1024 * 1024;
  unsigned short* Woth = Wvtl + 1024 * 1024;
  unsigned short* Wotl = Woth + 1024 * 1024;             // ends at 48MB
  unsigned short* Qh = (unsigned short*)(ws + 48 * MB);
  unsigned short* Ql = (unsigned short*)(ws + 64 * MB);
  unsigned short* Kh = (unsigned short*)(ws + 80 * MB);
  unsigned short* Kl = (unsigned short*)(ws + 96 * MB);
  unsigned short* Vth = (unsigned short*)(ws + 112 * MB);
  unsigned short* Vtl = (unsigned short*)(ws + 128 * MB);

  const int n4 = BATCH * S_LEN * D_DIM / 4;
  k_split<<<(n4 + 255) / 256, 256, 0, stream>>>((const float4*)X, (ushort4*)Xh,
                                                (ushort4*)Xl, n4);
  dim3 wtg(16, 16);
  k_wt<<<wtg, 256, 0, stream>>>(Wq, Wqth, Wqtl);
  k_wt<<<wtg, 256, 0, stream>>>(Wk, Wkth, Wktl);
  k_wt<<<wtg, 256, 0, stream>>>(Wv, Wvth, Wvtl);
  k_wt<<<wtg, 256, 0, stream>>>(Wo, Woth, Wotl);

  // fused QKV projection: grid (m, mat*8+n); m on x => A-row XCD locality
  gemm_qkv<<<dim3(64, 24), 256, 65536, stream>>>(
      Xh, Xl, Wqth, Wqtl, Wkth, Wktl, Wvth, Wvtl, Qh, Ql, Kh, Kl, Vth, Vtl);

  // grid.x = (b,h): all q-blocks of one (b,h) share linear%8 -> same XCD L2
  dim3 ag(BATCH * NH, S_LEN / 128);  // 64 x 16
  attn5<<<ag, 256, 0, stream>>>(Qh, Ql, Kh, Kl, Vth, Vtl, mask, Xh, Xl);

  gemm_wo<<<dim3(64, 8), 256, 65536, stream>>>(Xh, Xl, Woth, Wotl, out);
}

// Round 9
// 503.602 us; speedup vs baseline: 1.0414x; 1.0414x over previous
//
#include <hip/hip_runtime.h>
#include <hip/hip_bf16.h>
#include <stdint.h>

// Problem constants (from reference): B=4, S=2048, D=1024, H=16, DK=64
#define S_LEN 2048
#define D_DIM 1024
#define NH    16
#define DKH   64
#define BATCH 4

typedef __bf16 bf16x8 __attribute__((ext_vector_type(8)));
typedef float  f32x4  __attribute__((ext_vector_type(4)));

// RNE float->bf16 via native cast (compiler emits v_cvt_pk_bf16_f32)
__device__ __forceinline__ unsigned short f2bf(float x) {
  return __builtin_bit_cast(unsigned short, (__bf16)x);
}
__device__ __forceinline__ float bf2f(unsigned short b) {
  return __uint_as_float(((unsigned)b) << 16);
}

// async global->LDS, 16B per lane. LDS dest is wave-uniform base + lane*16.
__device__ __forceinline__ void gll16(const void* g, void* l) {
  __builtin_amdgcn_global_load_lds((const __attribute__((address_space(1))) unsigned*)g,
                                   (__attribute__((address_space(3))) unsigned*)l, 16, 0, 0);
}

#define MFMA(a, b, c) __builtin_amdgcn_mfma_f32_16x16x32_bf16(a, b, c, 0, 0, 0)

// ---------------------------------------------------------------------------
// Convert fp32 -> bf16 hi/lo, elementwise (for X / inputs), 4 floats/thread
// ---------------------------------------------------------------------------
__global__ void k_split(const float4* __restrict__ x, ushort4* __restrict__ hi,
                        ushort4* __restrict__ lo, int n4) {
  int i = blockIdx.x * 256 + threadIdx.x;
  if (i >= n4) return;
  float4 v = x[i];
  ushort4 h, l;
  h.x = f2bf(v.x); l.x = f2bf(v.x - bf2f(h.x));
  h.y = f2bf(v.y); l.y = f2bf(v.y - bf2f(h.y));
  h.z = f2bf(v.z); l.z = f2bf(v.z - bf2f(h.z));
  h.w = f2bf(v.w); l.w = f2bf(v.w - bf2f(h.w));
  hi[i] = h;
  lo[i] = l;
}

// ---------------------------------------------------------------------------
// Convert + transpose weights: W[K][N] fp32 -> Wt hi/lo [N][K] bf16.
// One launch for all 4 weights: blockIdx.z selects the matrix.
// ---------------------------------------------------------------------------
__global__ void k_wt4(const float* __restrict__ W0, const float* __restrict__ W1,
                      const float* __restrict__ W2, const float* __restrict__ W3,
                      unsigned short* __restrict__ h0, unsigned short* __restrict__ l0,
                      unsigned short* __restrict__ h1, unsigned short* __restrict__ l1,
                      unsigned short* __restrict__ h2, unsigned short* __restrict__ l2,
                      unsigned short* __restrict__ h3, unsigned short* __restrict__ l3) {
  __shared__ float t[64][65];
  const int z = blockIdx.z;
  const float* W = z == 0 ? W0 : z == 1 ? W1 : z == 2 ? W2 : W3;
  unsigned short* hi = z == 0 ? h0 : z == 1 ? h1 : z == 2 ? h2 : h3;
  unsigned short* lo = z == 0 ? l0 : z == 1 ? l1 : z == 2 ? l2 : l3;
  const int tid = threadIdx.x;
  const int k0 = blockIdx.x * 64, n0 = blockIdx.y * 64;
#pragma unroll
  for (int i = 0; i < 16; i++) {
    int idx = i * 256 + tid;
    int r = idx >> 6, c = idx & 63;
    t[r][c] = W[(size_t)(k0 + r) * D_DIM + n0 + c];
  }
  __syncthreads();
#pragma unroll
  for (int i = 0; i < 16; i++) {
    int idx = i * 256 + tid;
    int r = idx >> 6, c = idx & 63;
    float v = t[c][r];  // = W[k0+c][n0+r]
    unsigned short h = f2bf(v);
    size_t o = (size_t)(n0 + r) * D_DIM + k0 + c;
    hi[o] = h;
    lo[o] = f2bf(v - bf2f(h));
  }
}

// ---------------------------------------------------------------------------
// Shared hi/lo 3-pass GEMM core: computes a 128x128 C tile at (m0, n0) from
// A (hi/lo, [8192][1024]) and Bt (hi/lo, [N][K] transposed weights).
// Results left in acc[4][4] (wave-level 2x2 of 64x64).
// ---------------------------------------------------------------------------
__device__ __forceinline__ void gemm_core(
    const unsigned short* __restrict__ Ahi, const unsigned short* __restrict__ Alo,
    const unsigned short* __restrict__ Bth, const unsigned short* __restrict__ Btl,
    int m0, int n0, char* smem, f32x4 (&acc)[4][4]) {
  constexpr int K = 1024;
  char* sAh = smem;
  char* sAl = smem + 16384;
  char* sBh = smem + 32768;
  char* sBl = smem + 49152;

  const int tid = threadIdx.x;
  const int lane = tid & 63, w = tid >> 6;
  const int wr = w >> 1, wc = w & 1;

  int gofs[4], lofs[4];
#pragma unroll
  for (int i = 0; i < 4; i++) {
    int c = (w * 4 + i) * 64 + lane;
    int row = c >> 3, s = c & 7;
    int sp = s ^ (row & 7);
    gofs[i] = row * K + sp * 8;
    lofs[i] = (w * 4 + i) * 1024;
  }
  const unsigned short* pAh = Ahi + (size_t)m0 * K;
  const unsigned short* pAl = Alo + (size_t)m0 * K;
  const unsigned short* pBh = Bth + (size_t)n0 * K;
  const unsigned short* pBl = Btl + (size_t)n0 * K;

  for (int kt = 0; kt < K / 64; ++kt) {
    const int ko = kt * 64;
#pragma unroll
    for (int i = 0; i < 4; i++) {
      gll16(pAh + ko + gofs[i], sAh + lofs[i]);
      gll16(pAl + ko + gofs[i], sAl + lofs[i]);
      gll16(pBh + ko + gofs[i], sBh + lofs[i]);
      gll16(pBl + ko + gofs[i], sBl + lofs[i]);
    }
    __syncthreads();
#pragma unroll
    for (int kk = 0; kk < 2; kk++) {
      bf16x8 ah[4], al[4], bh[4], bl[4];
      const int cch = kk * 4 + (lane >> 4);
#pragma unroll
      for (int mr = 0; mr < 4; mr++) {
        int row = wr * 64 + mr * 16 + (lane & 15);
        int off = row * 128 + ((cch ^ (row & 7)) << 4);
        ah[mr] = *(const bf16x8*)(sAh + off);
        al[mr] = *(const bf16x8*)(sAl + off);
      }
#pragma unroll
      for (int nr = 0; nr < 4; nr++) {
        int row = wc * 64 + nr * 16 + (lane & 15);
        int off = row * 128 + ((cch ^ (row & 7)) << 4);
        bh[nr] = *(const bf16x8*)(sBh + off);
        bl[nr] = *(const bf16x8*)(sBl + off);
      }
#pragma unroll
      for (int mr = 0; mr < 4; mr++)
#pragma unroll
        for (int nr = 0; nr < 4; nr++) {
          acc[mr][nr] = MFMA(ah[mr], bh[nr], acc[mr][nr]);
          acc[mr][nr] = MFMA(ah[mr], bl[nr], acc[mr][nr]);
          acc[mr][nr] = MFMA(al[mr], bh[nr], acc[mr][nr]);
        }
    }
    __syncthreads();
  }
}

// ---------------------------------------------------------------------------
// Fused QKV projection. grid = (64 m-tiles, 24 = mat*8 + n-tile).
// m on blockIdx.x => all 24 blocks of an m-row have id%8 equal -> same XCD,
// so the A-row (hi+lo, 512KB) is fetched once per XCD (L2-local).
// mat 0: Q (escale 1) -> Qh/Ql [M][N];  mat 1: K (escale 1/8) -> Kh/Kl;
// mat 2: V -> Vt hi/lo [b][h][d][s].
// ---------------------------------------------------------------------------
__global__ __launch_bounds__(256, 2) void gemm_qkv(
    const unsigned short* __restrict__ Ahi, const unsigned short* __restrict__ Alo,
    const unsigned short* __restrict__ Wqh, const unsigned short* __restrict__ Wql,
    const unsigned short* __restrict__ Wkh, const unsigned short* __restrict__ Wkl,
    const unsigned short* __restrict__ Wvh, const unsigned short* __restrict__ Wvl,
    unsigned short* __restrict__ Qh, unsigned short* __restrict__ Ql,
    unsigned short* __restrict__ Kh, unsigned short* __restrict__ Kl,
    unsigned short* __restrict__ Vth, unsigned short* __restrict__ Vtl) {
  constexpr int N = 1024;
  extern __shared__ char smem[];
  const int m0 = blockIdx.x * 128;
  const int mat = blockIdx.y >> 3;
  const int n0 = (blockIdx.y & 7) * 128;

  const unsigned short* Bth = mat == 0 ? Wqh : mat == 1 ? Wkh : Wvh;
  const unsigned short* Btl = mat == 0 ? Wql : mat == 1 ? Wkl : Wvl;
  unsigned short* Chi = mat == 0 ? Qh : mat == 1 ? Kh : Vth;
  unsigned short* Clo = mat == 0 ? Ql : mat == 1 ? Kl : Vtl;
  const float esc = mat == 1 ? 0.125f : 1.0f;

  f32x4 acc[4][4] = {};
  gemm_core(Ahi, Alo, Bth, Btl, m0, n0, smem, acc);

  const int lane = threadIdx.x & 63, w = threadIdx.x >> 6;
  const int wr = w >> 1, wc = w & 1;
#pragma unroll
  for (int mr = 0; mr < 4; mr++)
#pragma unroll
    for (int nr = 0; nr < 4; nr++)
#pragma unroll
      for (int j = 0; j < 4; j++) {
        int row = m0 + wr * 64 + mr * 16 + (lane >> 4) * 4 + j;
        int col = n0 + wc * 64 + nr * 16 + (lane & 15);
        float v = acc[mr][nr][j];
        if (mat < 2) {
          v *= esc;
          size_t o = (size_t)row * N + col;
          unsigned short hh = f2bf(v);
          Chi[o] = hh;
          Clo[o] = f2bf(v - bf2f(hh));
        } else {
          int bi = row >> 11, s = row & (S_LEN - 1);
          int hh2 = col >> 6, d = col & (DKH - 1);
          size_t o = ((size_t)(bi * NH + hh2) * DKH + d) * S_LEN + s;
          unsigned short hh = f2bf(v);
          Chi[o] = hh;
          Clo[o] = f2bf(v - bf2f(hh));
        }
      }
}

// ---------------------------------------------------------------------------
// Final GEMM (O @ Wo), fp32 out. m on blockIdx.x (grid 64 x 8) for XCD
// locality of A rows.
// ---------------------------------------------------------------------------
__global__ __launch_bounds__(256, 2) void gemm_wo(
    const unsigned short* __restrict__ Ahi, const unsigned short* __restrict__ Alo,
    const unsigned short* __restrict__ Bth, const unsigned short* __restrict__ Btl,
    float* __restrict__ Cf) {
  constexpr int N = 1024;
  extern __shared__ char smem[];
  const int m0 = blockIdx.x * 128, n0 = blockIdx.y * 128;

  f32x4 acc[4][4] = {};
  gemm_core(Ahi, Alo, Bth, Btl, m0, n0, smem, acc);

  const int lane = threadIdx.x & 63, w = threadIdx.x >> 6;
  const int wr = w >> 1, wc = w & 1;
#pragma unroll
  for (int mr = 0; mr < 4; mr++)
#pragma unroll
    for (int nr = 0; nr < 4; nr++)
#pragma unroll
      for (int j = 0; j < 4; j++) {
        int row = m0 + wr * 64 + mr * 16 + (lane >> 4) * 4 + j;
        int col = n0 + wc * 64 + nr * 16 + (lane & 15);
        Cf[(size_t)row * N + col] = acc[mr][nr][j];
      }
}

// ---------------------------------------------------------------------------
// Flash attention v4 (verified 203us config): double-buffered K/V prefetch,
// ONE barrier per tile, KVBLK=64, LDS 80KB -> 2 blocks/CU.
// Cheap softmax (no max-tracking, deferred row-sum, K pre-scaled by 1/8).
// Block = 256 thr = 4 waves, 128 q rows (wave owns 32). grid.x = (b,h).
// QK^T 3-pass hi/lo (48 MFMA/tile/wave); PV 2-pass (32 MFMA/tile/wave).
// ---------------------------------------------------------------------------
__global__ __launch_bounds__(256, 2) void attn4(
    const unsigned short* __restrict__ Qh, const unsigned short* __restrict__ Ql,
    const unsigned short* __restrict__ Kh, const unsigned short* __restrict__ Kl,
    const unsigned short* __restrict__ Vth, const unsigned short* __restrict__ Vtl,
    const int* __restrict__ mask,
    unsigned short* __restrict__ Oh, unsigned short* __restrict__ Ol) {
  __shared__ char sKh0[8192], sKl0[8192], sVh0[8192], sVl0[8192];
  __shared__ char sKh1[8192], sKl1[8192], sVh1[8192], sVl1[8192];
  __shared__ char sP[4][4096];  // per-wave P hi: [32 rows][64 keys] bf16, swizzled

  const int tid = threadIdx.x, lane = tid & 63, w = tid >> 6;
  const int bh = blockIdx.x, b = bh >> 4, h = bh & (NH - 1);
  const int q0 = blockIdx.y * 128 + w * 32;
  const int lo16 = lane & 15, hi4 = lane >> 4;

  bf16x8 qh[2][2], ql[2][2];
#pragma unroll
  for (int g = 0; g < 2; g++)
#pragma unroll
    for (int kk = 0; kk < 2; kk++) {
      size_t base = ((size_t)(b * S_LEN + q0 + g * 16 + lo16)) * D_DIM + h * DKH + kk * 32 + hi4 * 8;
      qh[g][kk] = *(const bf16x8*)(Qh + base);
      ql[g][kk] = *(const bf16x8*)(Ql + base);
    }

  int srowK[2], scolK[2], lofs[2];
#pragma unroll
  for (int i = 0; i < 2; i++) {
    int c = (w * 2 + i) * 64 + lane;  // 0..511
    int row = c >> 3, s = c & 7;
    srowK[i] = row;
    scolK[i] = (s ^ (row & 7)) * 8;
    lofs[i] = c * 16 - lane * 16;  // wave-uniform base part
  }

  float lsum[2][4] = {};
  f32x4 oacc[2][4] = {};
  char* sPw = sP[w];

  const size_t kbase = (size_t)b * S_LEN * D_DIM + h * DKH;
  const size_t vbase = (size_t)bh * DKH * S_LEN;
  const int* mrow = mask + b * S_LEN;

  auto STAGE = [&](char* dKh, char* dKl, char* dVh, char* dVl, int sk0) {
#pragma unroll
    for (int i = 0; i < 2; i++) {
      size_t gk = kbase + (size_t)(sk0 + srowK[i]) * D_DIM + scolK[i];
      gll16(Kh + gk, dKh + lofs[i]);
      gll16(Kl + gk, dKl + lofs[i]);
      size_t gv = vbase + (size_t)srowK[i] * S_LEN + sk0 + scolK[i];
      gll16(Vth + gv, dVh + lofs[i]);
      gll16(Vtl + gv, dVl + lofs[i]);
    }
  };

  auto COMPUTE = [&](const char* cKh, const char* cKl, const char* cVh,
                     const char* cVl, int sk0) {
    f32x4 sc[2][4] = {};
    __builtin_amdgcn_s_setprio(1);
#pragma unroll
    for (int nr = 0; nr < 4; nr++) {
      int row = nr * 16 + lo16;
      int off0 = row * 128 + ((hi4 ^ (row & 7)) << 4);
      int off1 = row * 128 + (((4 + hi4) ^ (row & 7)) << 4);
      bf16x8 kh0 = *(const bf16x8*)(cKh + off0);
      bf16x8 kh1 = *(const bf16x8*)(cKh + off1);
      bf16x8 kl0 = *(const bf16x8*)(cKl + off0);
      bf16x8 kl1 = *(const bf16x8*)(cKl + off1);
#pragma unroll
      for (int g = 0; g < 2; g++) {
        sc[g][nr] = MFMA(qh[g][0], kh0, sc[g][nr]);
        sc[g][nr] = MFMA(qh[g][1], kh1, sc[g][nr]);
        sc[g][nr] = MFMA(qh[g][0], kl0, sc[g][nr]);
        sc[g][nr] = MFMA(qh[g][1], kl1, sc[g][nr]);
        sc[g][nr] = MFMA(ql[g][0], kh0, sc[g][nr]);
        sc[g][nr] = MFMA(ql[g][1], kh1, sc[g][nr]);
      }
    }
    __builtin_amdgcn_s_setprio(0);

#pragma unroll
    for (int nr = 0; nr < 4; nr++) {
      float bias = mrow[sk0 + nr * 16 + lo16] ? 0.f : -1e9f;
#pragma unroll
      for (int g = 0; g < 2; g++)
#pragma unroll
        for (int j = 0; j < 4; j++) {
          float p = __expf(sc[g][nr][j] + bias);
          lsum[g][j] += p;
          int row = g * 16 + hi4 * 4 + j;
          int colb = (nr * 16 + lo16) * 2;
          *(unsigned short*)(sPw + row * 128 + (colb ^ ((row & 7) << 4))) = f2bf(p);
        }
    }

    bf16x8 pa[2][2];
#pragma unroll
    for (int g = 0; g < 2; g++)
#pragma unroll
      for (int kk = 0; kk < 2; kk++) {
        int row = g * 16 + lo16;
        int colb = kk * 64 + hi4 * 16;
        pa[g][kk] = *(const bf16x8*)(sPw + row * 128 + (colb ^ ((row & 7) << 4)));
      }

    __builtin_amdgcn_s_setprio(1);
#pragma unroll
    for (int kk = 0; kk < 2; kk++)
#pragma unroll
      for (int f = 0; f < 4; f++) {
        int vrow = f * 16 + lo16;
        int voff = vrow * 128 + (((kk * 4 + hi4) ^ (vrow & 7)) << 4);
        bf16x8 vh = *(const bf16x8*)(cVh + voff);
        bf16x8 vl = *(const bf16x8*)(cVl + voff);
#pragma unroll
        for (int g = 0; g < 2; g++) {
          oacc[g][f] = MFMA(pa[g][kk], vh, oacc[g][f]);
          oacc[g][f] = MFMA(pa[g][kk], vl, oacc[g][f]);
        }
      }
    __builtin_amdgcn_s_setprio(0);
  };

  STAGE(sKh0, sKl0, sVh0, sVl0, 0);
  __syncthreads();

  for (int kt = 0; kt < S_LEN / 64; kt += 2) {
    const int sk0 = kt * 64;
    STAGE(sKh1, sKl1, sVh1, sVl1, sk0 + 64);
    COMPUTE(sKh0, sKl0, sVh0, sVl0, sk0);
    __syncthreads();
    if (kt + 2 < S_LEN / 64) STAGE(sKh0, sKl0, sVh0, sVl0, sk0 + 128);
    COMPUTE(sKh1, sKl1, sVh1, sVl1, sk0 + 64);
    __syncthreads();
  }

  float inv[2][4];
#pragma unroll
  for (int g = 0; g < 2; g++)
#pragma unroll
    for (int j = 0; j < 4; j++) {
      float s = lsum[g][j];
      s += __shfl_xor(s, 1);
      s += __shfl_xor(s, 2);
      s += __shfl_xor(s, 4);
      s += __shfl_xor(s, 8);
      inv[g][j] = 1.f / s;
    }

#pragma unroll
  for (int g = 0; g < 2; g++)
#pragma unroll
    for (int f = 0; f < 4; f++)
#pragma unroll
      for (int j = 0; j < 4; j++) {
        int row = q0 + g * 16 + hi4 * 4 + j;
        int col = h * DKH + f * 16 + lo16;
        float v = oacc[g][f][j] * inv[g][j];
        size_t o = ((size_t)(b * S_LEN + row)) * D_DIM + col;
        unsigned short hh = f2bf(v);
        Oh[o] = hh;
        Ol[o] = f2bf(v - bf2f(hh));
      }
}

// ---------------------------------------------------------------------------
extern "C" void kernel_launch(void* const* d_in, const int* in_sizes, int n_in,
                              void* d_out, int out_size, void* d_ws, size_t ws_size,
                              hipStream_t stream) {
  const float* X = (const float*)d_in[0];
  const int* mask = (const int*)d_in[1];
  const float* Wq = (const float*)d_in[2];
  const float* Wk = (const float*)d_in[3];
  const float* Wv = (const float*)d_in[4];
  const float* Wo = (const float*)d_in[5];
  float* out = (float*)d_out;

  const size_t MB = 1024 * 1024;
  if (ws_size < 144 * MB) return;  // insufficient scratch -> visible failure

  char* ws = (char*)d_ws;
  unsigned short* Xh = (unsigned short*)(ws);            // 16MB  (later Oh)
  unsigned short* Xl = (unsigned short*)(ws + 16 * MB);  // 16MB  (later Ol)
  unsigned short* Wqth = (unsigned short*)(ws + 32 * MB);
  unsigned short* Wqtl = Wqth + 1024 * 1024;
  unsigned short* Wkth = Wqtl + 1024 * 1024;
  unsigned short* Wktl = Wkth + 1024 * 1024;
  unsigned short* Wvth = Wktl + 1024 * 1024;
  unsigned short* Wvtl = Wvth + 1024 * 1024;
  unsigned short* Woth = Wvtl + 1024 * 1024;
  unsigned short* Wotl = Woth + 1024 * 1024;             // ends at 48MB
  unsigned short* Qh = (unsigned short*)(ws + 48 * MB);
  unsigned short* Ql = (unsigned short*)(ws + 64 * MB);
  unsigned short* Kh = (unsigned short*)(ws + 80 * MB);
  unsigned short* Kl = (unsigned short*)(ws + 96 * MB);
  unsigned short* Vth = (unsigned short*)(ws + 112 * MB);
  unsigned short* Vtl = (unsigned short*)(ws + 128 * MB);

  const int n4 = BATCH * S_LEN * D_DIM / 4;
  k_split<<<(n4 + 255) / 256, 256, 0, stream>>>((const float4*)X, (ushort4*)Xh,
                                                (ushort4*)Xl, n4);
  k_wt4<<<dim3(16, 16, 4), 256, 0, stream>>>(Wq, Wk, Wv, Wo,
                                             Wqth, Wqtl, Wkth, Wktl,
                                             Wvth, Wvtl, Woth, Wotl);

  // fused QKV projection: grid (m, mat*8+n); m on x => A-row XCD locality
  gemm_qkv<<<dim3(64, 24), 256, 65536, stream>>>(
      Xh, Xl, Wqth, Wqtl, Wkth, Wktl, Wvth, Wvtl, Qh, Ql, Kh, Kl, Vth, Vtl);

  // grid.x = (b,h): all q-blocks of one (b,h) share linear%8 -> same XCD L2
  dim3 ag(BATCH * NH, S_LEN / 128);  // 64 x 16
  attn4<<<ag, 256, 0, stream>>>(Qh, Ql, Kh, Kl, Vth, Vtl, mask, Xh, Xl);

  gemm_wo<<<dim3(64, 8), 256, 65536, stream>>>(Xh, Xl, Woth, Wotl, out);
}